// Round 7
// baseline (43.161 us; speedup 1.0000x reference)
//
#include <hip/hip_runtime.h>

// Problem constants (B, C, O, K, H, W) = (8, 64, 64, 3, 128, 128)
#define NTAP 9
#define C_DIM 64
#define O_DIM 64
#define HW 128
#define CPAD 72   // LDS w-row stride 144B: 16B-aligned, minimal bank aliasing

typedef short s16x8 __attribute__((ext_vector_type(8)));
typedef float f32x16 __attribute__((ext_vector_type(16)));

__device__ __forceinline__ unsigned short f2bf(float x) {
    unsigned int u = __float_as_uint(x);
    unsigned int r = (u + 0x7fffu + ((u >> 16) & 1u)) >> 16;
    return (unsigned short)r;
}

// ---------------------------------------------------------------------------
// Pre-kernel: W [C=64][3][3][O=64] f32 -> fragment-major bf16 (d_ws, 72KB).
// Fragment F = ((tap*4 + s)*2 + m)*64 + lane, element e:
//   c = 16*s + 8*(lane>>5) + e,   o = 32*m + (lane&31)
// Same (lane>>5, e) -> k-slot mapping is used for the feat (B) operand, so the
// contraction is correct under any hardware k-slot permutation.
// ---------------------------------------------------------------------------
__global__ void swizzle_W_kernel(const float* __restrict__ W,
                                 unsigned short* __restrict__ Wf) {
    int idx = blockIdx.x * 256 + threadIdx.x;
    if (idx >= NTAP * 4 * 2 * 64 * 8) return;
    int e    = idx & 7;
    int lane = (idx >> 3) & 63;
    int m    = (idx >> 9) & 1;
    int s    = (idx >> 10) & 3;
    int tap  = idx >> 12;
    int c = s * 16 + ((lane >> 5) << 3) + e;
    int o = (m << 5) + (lane & 31);
    Wf[idx] = f2bf(W[c * 576 + tap * 64 + o]);
}

// ---------------------------------------------------------------------------
// Main kernel: one block per (batch, 8h x 32w patch-PAIR). 256 threads.
// Two 8x16 patches, double-buffered LDS windows [2][10][18][72] (51.8KB).
// Pipeline: stage(p0); bar; { stage(p1) ; compute(p0) }; bar; compute(p1).
// Staging: per (row, c-octet), 6 aligned float4 spans cover [w0-4, w0+20)
// including both halos -- no separate scalar halo pass.
// Wave v: MFMA B-cols = pixels {rows 2v,2v+1} x {w0..w0+15}, all 64 o.
// ---------------------------------------------------------------------------
__global__ __launch_bounds__(256, 4) void dyconv_kernel(
    const float* __restrict__ feat, const float* __restrict__ tm,
    const unsigned short* __restrict__ Wf, float* __restrict__ out)
{
    __shared__ __align__(16) unsigned short feat_lds[2][10][18][CPAD];

    // bijective XCD swizzle: XCD x gets batch x (feat[b] = 4.2MB ~ one L2)
    const int flat  = blockIdx.x;             // 0..511
    const int b     = flat & 7;
    const int inner = flat >> 3;              // 0..63
    const int h0    = (inner >> 2) * 8;       // 0..120
    const int w0p   = (inner & 3) * 32;       // pair base w: 0,32,64,96

    const int tid = threadIdx.x;

    // ---- stage one 8x16 patch window (10r x 18w x 64c) into buf ----
    auto stage = [&](int buf, int w0) {
        for (int U = tid; U < 480; U += 256) {       // 10 r x 6 quads x 8 octets
            const int r    = U / 48;
            const int rem  = U % 48;
            const int q    = rem % 6;                // w-quad: wb = w0-4+4q
            const int c0   = (rem / 6) * 8;          // c-octet base
            const int hr   = h0 - 1 + r;
            const int wb   = w0 - 4 + 4 * q;
            const bool ld  = (hr >= 0) && (hr < HW) && (wb >= 0) && (wb <= HW - 4);
            const float* src = feat + (((size_t)(b * C_DIM + c0)) * HW + hr) * HW + wb;
            float4 v[8];
            #pragma unroll
            for (int j = 0; j < 8; ++j)
                v[j] = ld ? *(const float4*)(src + (size_t)j * (HW * HW))
                          : float4{0.f, 0.f, 0.f, 0.f};
            #pragma unroll
            for (int i = 0; i < 4; ++i) {
                const int wi = 4 * q - 3 + i;        // window index = w-(w0-1)
                if (wi >= 0 && wi <= 17) {
                    s16x8 pk;
                    #pragma unroll
                    for (int j = 0; j < 8; ++j) {
                        const float* vf = (const float*)&v[j];
                        pk[j] = (short)f2bf(vf[i]);
                    }
                    *(s16x8*)&feat_lds[buf][r][wi][c0] = pk;
                }
            }
        }
    };

    const int lane = tid & 63;
    const int wave = tid >> 6;                 // 0..3
    const int g    = lane >> 5;                // k-slot half
    const int c31  = lane & 31;                // MFMA column = pixel index
    const int prow = c31 >> 4;                 // pixel row within pair
    const int pw   = c31 & 15;                 // pixel w within patch
    const int hout = h0 + wave * 2 + prow;
    const int lrow = wave * 2 + prow;          // base LDS row for di=0

    const s16x8* __restrict__ Wf8 = (const s16x8*)Wf;

    stage(0, w0p);
    __syncthreads();

    #pragma unroll
    for (int pp = 0; pp < 2; ++pp) {
        const int w0   = w0p + pp * 16;
        const int wout = w0 + pw;

        // prefetch tm scalars for this patch (in flight under staging)
        float tmr[NTAP];
        #pragma unroll
        for (int t = 0; t < NTAP; ++t)
            tmr[t] = tm[((size_t)(b * NTAP + t)) * (HW * HW)
                        + (size_t)hout * HW + wout];

        if (pp == 0) stage(1, w0p + 16);       // overlaps compute(p0) across waves

        f32x16 acc0 = {0,0,0,0,0,0,0,0,0,0,0,0,0,0,0,0};
        f32x16 acc1 = acc0;

        __builtin_amdgcn_s_setprio(1);
        #pragma unroll
        for (int tap = 0; tap < NTAP; ++tap) {
            const int di = tap / 3;
            const int dj = tap % 3;
            const s16x8* bp = (const s16x8*)&feat_lds[pp][lrow + di][pw + dj][0];
            f32x16 pa = {0,0,0,0,0,0,0,0,0,0,0,0,0,0,0,0};
            f32x16 pb = pa;
            #pragma unroll
            for (int s = 0; s < 4; ++s) {
                s16x8 bf = bp[2 * s + g];
                s16x8 a0 = Wf8[((tap * 4 + s) * 2 + 0) * 64 + lane];
                s16x8 a1 = Wf8[((tap * 4 + s) * 2 + 1) * 64 + lane];
                pa = __builtin_amdgcn_mfma_f32_32x32x16_bf16(a0, bf, pa, 0, 0, 0);
                pb = __builtin_amdgcn_mfma_f32_32x32x16_bf16(a1, bf, pb, 0, 0, 0);
            }
            const float tv = tmr[tap];
            #pragma unroll
            for (int r = 0; r < 16; ++r) {
                acc0[r] = fmaf(tv, pa[r], acc0[r]);
                acc1[r] = fmaf(tv, pb[r], acc1[r]);
            }
        }
        __builtin_amdgcn_s_setprio(0);

        // store: D (32x32) layout: col = lane&31 (pixel), o = (r&3)+8*(r>>2)+4*g
        float* op = out + ((size_t)b * O_DIM) * (HW * HW)
                  + (size_t)hout * HW + wout;
        #pragma unroll
        for (int r = 0; r < 16; ++r) {
            const int o = (r & 3) + ((r >> 2) << 3) + (g << 2);
            op[(size_t)o        * (HW * HW)] = acc0[r];
            op[(size_t)(o + 32) * (HW * HW)] = acc1[r];
        }

        if (pp == 0) __syncthreads();          // buf1 writes visible before compute(p1)
    }
}

extern "C" void kernel_launch(void* const* d_in, const int* in_sizes, int n_in,
                              void* d_out, int out_size, void* d_ws, size_t ws_size,
                              hipStream_t stream) {
    const float* feat = (const float*)d_in[0];   // [8,64,128,128] f32
    const float* tm   = (const float*)d_in[1];   // [8,9,16384]    f32
    const float* W    = (const float*)d_in[2];   // [64,3,3,64]    f32
    float* out        = (float*)d_out;           // [8,64,128,128] f32
    unsigned short* Wf = (unsigned short*)d_ws;  // 73728 B scratch

    swizzle_W_kernel<<<dim3(144), dim3(256), 0, stream>>>(W, Wf);
    dyconv_kernel<<<dim3(512), dim3(256), 0, stream>>>(feat, tm, Wf, out);
}

// Round 8
// 31.127 us; speedup vs baseline: 1.3866x; 1.3866x over previous
//
#include <hip/hip_runtime.h>

// Problem constants (B, C, O, K, H, W) = (8, 64, 64, 3, 128, 128)
#define NTAP 9
#define C_DIM 64
#define O_DIM 64
#define HW 128
#define CPAD 72   // LDS w-row stride 144B: 16B-aligned, 4-way worst-case banks

typedef short s16x8 __attribute__((ext_vector_type(8)));
typedef float f32x16 __attribute__((ext_vector_type(16)));

__device__ __forceinline__ unsigned short f2bf(float x) {
    unsigned int u = __float_as_uint(x);
    unsigned int r = (u + 0x7fffu + ((u >> 16) & 1u)) >> 16;
    return (unsigned short)r;
}

// ---------------------------------------------------------------------------
// Pre-kernel: W [C=64][3][3][O=64] f32 -> fragment-major bf16 (d_ws, 72KB).
// Fragment F = ((tap*4 + s)*2 + m)*64 + lane, element e:
//   c = 16*s + 8*(lane>>5) + e,   o = 32*m + (lane&31)
// Same (lane>>5, e) -> k-slot mapping is used for the feat (B) operand, so the
// contraction is correct under any hardware k-slot permutation.
// ---------------------------------------------------------------------------
__global__ void swizzle_W_kernel(const float* __restrict__ W,
                                 unsigned short* __restrict__ Wf) {
    int idx = blockIdx.x * 256 + threadIdx.x;
    if (idx >= NTAP * 4 * 2 * 64 * 8) return;
    int e    = idx & 7;
    int lane = (idx >> 3) & 63;
    int m    = (idx >> 9) & 1;
    int s    = (idx >> 10) & 3;
    int tap  = idx >> 12;
    int c = s * 16 + ((lane >> 5) << 3) + e;
    int o = (m << 5) + (lane & 31);
    Wf[idx] = f2bf(W[c * 576 + tap * 64 + o]);
}

// ---------------------------------------------------------------------------
// Main kernel: one block per (batch, row h, 64-w half). 256 threads = 4 waves.
// LDS window: 3 rows x 66 w x 64 c bf16 (28.5KB) -> 4 blocks/CU resident,
// grid 2048 (8 gens) gives phase-staggered stage/compute overlap ACROSS blocks.
// Wave v: quadrant (o-half m = v>>1, px-group pg = v&1) -> 32 px x 32 o,
// a single 36-MFMA accumulator chain (9 taps x 4 c-chunks).
// ---------------------------------------------------------------------------
__global__ __launch_bounds__(256, 4) void dyconv_kernel(
    const float* __restrict__ feat, const float* __restrict__ tm,
    const unsigned short* __restrict__ Wf, float* __restrict__ out)
{
    __shared__ __align__(16) unsigned short feat_lds[3][66][CPAD];

    // bijective XCD swizzle: XCD x gets batch x; h/w neighbors adjacent in time
    const int flat  = blockIdx.x;             // 0..2047
    const int b     = flat & 7;
    const int inner = flat >> 3;              // 0..255
    const int h     = inner >> 1;             // 0..127
    const int w0    = (inner & 1) << 6;       // 0 or 64

    const int tid = threadIdx.x;

    // ---- stage rows h-1..h+1, w-span [w0-4, w0+68) x 64 c (halos included) ----
    // unit U = ((r*8 + oct)*18 + q): float4 span load of 4 w x 8 c, pack to bf16
    for (int U = tid; U < 432; U += 256) {
        const int q   = U % 18;               // w-quad: wb = w0-4+4q
        const int ro  = U / 18;
        const int oct = ro & 7;               // c-octet: c0 = oct*8
        const int r   = ro >> 3;              // input row 0..2 (hr = h-1+r)
        const int hr  = h - 1 + r;
        const int wb  = w0 - 4 + 4 * q;
        const bool ld = (hr >= 0) && (hr < HW) && (wb >= 0) && (wb <= HW - 4);
        const float* src = feat + (((size_t)(b * C_DIM + oct * 8)) * HW + hr) * HW + wb;
        float4 v[8];
        #pragma unroll
        for (int j = 0; j < 8; ++j)
            v[j] = ld ? *(const float4*)(src + (size_t)j * (HW * HW))
                      : float4{0.f, 0.f, 0.f, 0.f};
        #pragma unroll
        for (int i = 0; i < 4; ++i) {
            const int wi = 4 * q - 3 + i;     // window index = w_in - (w0-1)
            if (wi >= 0 && wi <= 65) {
                s16x8 pk;
                #pragma unroll
                for (int j = 0; j < 8; ++j) {
                    const float* vf = (const float*)&v[j];
                    pk[j] = (short)f2bf(vf[i]);
                }
                *(s16x8*)&feat_lds[r][wi][oct * 8] = pk;
            }
        }
    }

    const int lane = tid & 63;
    const int wave = tid >> 6;                // 0..3
    const int m    = wave >> 1;               // o-half
    const int pg   = wave & 1;                // px 32-group within the 64-w tile
    const int g    = lane >> 5;               // k-slot half
    const int c31  = lane & 31;               // MFMA column = pixel index
    const int wout = w0 + pg * 32 + c31;

    // prefetch tm scalars (independent of LDS; in flight across the barrier)
    float tmr[NTAP];
    #pragma unroll
    for (int t = 0; t < NTAP; ++t)
        tmr[t] = tm[((size_t)(b * NTAP + t)) * (HW * HW) + (size_t)h * HW + wout];

    __syncthreads();

    const s16x8* __restrict__ Wf8 = (const s16x8*)Wf;

    f32x16 acc = {0,0,0,0,0,0,0,0,0,0,0,0,0,0,0,0};

    __builtin_amdgcn_s_setprio(1);
    #pragma unroll
    for (int tap = 0; tap < NTAP; ++tap) {
        const int di = tap / 3;
        const int dj = tap % 3;
        const s16x8* bp = (const s16x8*)&feat_lds[di][pg * 32 + c31 + dj][0];
        f32x16 pa = {0,0,0,0,0,0,0,0,0,0,0,0,0,0,0,0};
        #pragma unroll
        for (int s = 0; s < 4; ++s) {
            s16x8 bf = bp[2 * s + g];                              // ds_read_b128
            s16x8 a  = Wf8[((tap * 4 + s) * 2 + m) * 64 + lane];   // L2-hot 16B
            pa = __builtin_amdgcn_mfma_f32_32x32x16_bf16(a, bf, pa, 0, 0, 0);
        }
        const float tv = tmr[tap];
        #pragma unroll
        for (int r = 0; r < 16; ++r)
            acc[r] = fmaf(tv, pa[r], acc[r]);
    }
    __builtin_amdgcn_s_setprio(0);

    // ---- store: D (32x32): col = lane&31 (pixel), o = (r&3)+8*(r>>2)+4*g+32*m
    float* op = out + ((size_t)b * O_DIM) * (HW * HW) + (size_t)h * HW + wout;
    #pragma unroll
    for (int r = 0; r < 16; ++r) {
        const int o = (r & 3) + ((r >> 2) << 3) + (g << 2) + (m << 5);
        op[(size_t)o * (HW * HW)] = acc[r];
    }
}

extern "C" void kernel_launch(void* const* d_in, const int* in_sizes, int n_in,
                              void* d_out, int out_size, void* d_ws, size_t ws_size,
                              hipStream_t stream) {
    const float* feat = (const float*)d_in[0];   // [8,64,128,128] f32
    const float* tm   = (const float*)d_in[1];   // [8,9,16384]    f32
    const float* W    = (const float*)d_in[2];   // [64,3,3,64]    f32
    float* out        = (float*)d_out;           // [8,64,128,128] f32
    unsigned short* Wf = (unsigned short*)d_ws;  // 73728 B scratch

    swizzle_W_kernel<<<dim3(144), dim3(256), 0, stream>>>(W, Wf);
    dyconv_kernel<<<dim3(2048), dim3(256), 0, stream>>>(feat, tm, Wf, out);
}